// Round 4
// baseline (597.994 us; speedup 1.0000x reference)
//
#include <hip/hip_runtime.h>
#include <hip/hip_cooperative_groups.h>

namespace cg = cooperative_groups;

// Problem constants: B=2, N=1024, U=V=512, F_IN=1, F=64, L=4
#define NTOT 1024
#define HALF 512

struct PrepS  { float tile[32][33]; };
struct EdgeS  { float adjr[4][1024]; float w[4][512]; float nfv[1024];
                float wef[64][64]; float ein[4][64]; };
struct LayerS { float wT[512][4]; float e[4][64]; float x[4][64];
                float part[4][4][64]; float agg[4][64]; float msg[4][64]; };
union SMem { PrepS p; EdgeS e; LayerS l; };

// One cooperative kernel: 512 blocks x 256 threads = exactly 2 blocks/CU.
// LDS 46 KB/block (union) -> 92 KB/CU < 160 KB; co-residency guaranteed.
__global__ void __launch_bounds__(256, 2) k_all(
    const float* __restrict__ nf, const float* __restrict__ adj,
    const float* __restrict__ wvu, const float* __restrict__ Wi,
    const float* __restrict__ bi, const float* __restrict__ Wee,
    const float* __restrict__ Wef, const float* __restrict__ Wm,
    const float* __restrict__ Wu, float* __restrict__ out,
    float* __restrict__ wvuT, float* __restrict__ x0buf,
    float* __restrict__ x1buf, float* __restrict__ edge,
    float* __restrict__ normf, float* __restrict__ partials,
    int* __restrict__ nmax)
{
    __shared__ SMem sm;
    cg::grid_group grid = cg::this_grid();
    const int bid = blockIdx.x, tid = threadIdx.x;
    const int g0 = bid * 4;
    const int b = g0 >> 10, i0 = g0 & 1023;
    const bool top = (i0 < 512);

    // ---------------- Phase A: norm partials + wvu transpose + x0 ----------
    if (bid == 0 && tid == 0) *nmax = 0;
    {
        int cb = bid >> 8, cc = (bid >> 6) & 3, rc = bid & 63;
        int col = cc * 256 + tid;
        const float* p = adj + (size_t)cb * NTOT * NTOT + (size_t)rc * 16 * NTOT + col;
        float s = 0.f;
#pragma unroll
        for (int r = 0; r < 16; ++r) s += 1.0f - p[(size_t)r * NTOT];
        partials[rc * 2048 + cb * NTOT + col] = s;
    }
    {
        int tb = bid >> 8, tyi = (bid >> 4) & 15, txi = bid & 15;
        int xb = txi * 32, yb = tyi * 32;
        const float* src = wvu + (size_t)tb * HALF * HALF;
        float* dst = wvuT + (size_t)tb * HALF * HALF;
        int tx = tid & 31, ty = tid >> 5; // 32 x 8
#pragma unroll
        for (int k = 0; k < 32; k += 8)
            sm.p.tile[ty + k][tx] = src[(size_t)(yb + ty + k) * HALF + xb + tx];
        __syncthreads();
#pragma unroll
        for (int k = 0; k < 32; k += 8)
            dst[(size_t)(xb + ty + k) * HALF + yb + tx] = sm.p.tile[tx][ty + k];
    }
    {
        int e = bid * 256 + tid;
        int f = e & 63, bn = e >> 6;
        x0buf[e] = fmaxf(fmaf(nf[bn], Wi[f], bi[f]), 0.f);
    }
    grid.sync();

    // ---------------- Phase B: finish norm (4 cols/block) + global max -----
    {
        int wv = tid >> 6, ln = tid & 63;
        int c = bid * 4 + wv; // 0..2047
        float s = partials[ln * 2048 + c];
#pragma unroll
        for (int o = 32; o > 0; o >>= 1) s += __shfl_xor(s, o, 64);
        if (ln == 0) {
            float v = fmaxf(s, 1.0f);
            normf[c] = v;
            atomicMax(nmax, __float_as_int(v));
        }
    }
    grid.sync();

    // ---------------- Phase C: edge embedding ------------------------------
    {
        const float4* src = (const float4*)(adj + (size_t)b * 1048576 + (size_t)i0 * 1024);
        float4* dst = (float4*)sm.e.adjr;
        for (int t = tid; t < 1024; t += 256) dst[t] = src[t];
        const float4* nsrc = (const float4*)(nf + b * 1024);
        ((float4*)sm.e.nfv)[tid] = nsrc[tid];
        const float* wsrc = top ? (wvuT + (size_t)b * 262144 + (size_t)i0 * 512)
                                : (wvu + (size_t)b * 262144 + (size_t)(i0 - 512) * 512);
        const float4* w4s = (const float4*)wsrc;
        float4* wds = (float4*)sm.e.w;
        for (int t = tid; t < 512; t += 256) wds[t] = w4s[t];
        const float4* wefs = (const float4*)Wef;
        float4* wefd = (float4*)sm.e.wef;
        for (int t = tid; t < 1024; t += 256) wefd[t] = wefs[t];
    }
    __syncthreads();
    {
        int lane = tid & 63, row = tid >> 6;
        int sameoff = top ? 0 : 512;
        int crossoff = top ? 512 : 0;
        // same-half (w==0) collapse: |W1k| * (W1k>0 ? Sp : Sm)
        float sp = 0.f, smv = 0.f;
#pragma unroll
        for (int it = 0; it < 8; ++it) {
            int j = sameoff + it * 64 + lane;
            float m = 1.0f - sm.e.adjr[row][j];
            float x = sm.e.nfv[j];
            sp = fmaf(m, fmaxf(x, 0.f), sp);
            smv = fmaf(m, fmaxf(-x, 0.f), smv);
        }
#pragma unroll
        for (int o = 32; o > 0; o >>= 1) {
            sp += __shfl_xor(sp, o, 64);
            smv += __shfl_xor(smv, o, 64);
        }
        float W0 = 0.f, W1 = 0.f;
        if (lane < 63) { W0 = Wee[lane]; W1 = Wee[63 + lane]; }
        float acc = fabsf(W1) * (W1 > 0.f ? sp : smv);
        const float* arow = &sm.e.adjr[row][crossoff];
        const float* nrow = &sm.e.nfv[crossoff];
        const float* wrow = &sm.e.w[row][0];
#pragma unroll 4
        for (int qq = 0; qq < 128; ++qq) {
            float4 a4 = *(const float4*)(arow + qq * 4);
            float4 w4 = *(const float4*)(wrow + qq * 4);
            float4 n4 = *(const float4*)(nrow + qq * 4);
            float c;
            c = fmaxf(fmaf(w4.x, W0, n4.x * W1), 0.f); acc = fmaf(1.0f - a4.x, c, acc);
            c = fmaxf(fmaf(w4.y, W0, n4.y * W1), 0.f); acc = fmaf(1.0f - a4.y, c, acc);
            c = fmaxf(fmaf(w4.z, W0, n4.z * W1), 0.f); acc = fmaf(1.0f - a4.z, c, acc);
            c = fmaxf(fmaf(w4.w, W0, n4.w * W1), 0.f); acc = fmaf(1.0f - a4.w, c, acc);
        }
        float nv = normf[b * 1024 + i0 + row];
        float nmaxv = __int_as_float(*nmax);
        float ein = (lane < 63) ? (acc * (1.0f / nv)) : (nv / nmaxv);
        sm.e.ein[row][lane] = ein;
        __syncthreads();
        float acc2 = 0.f;
#pragma unroll
        for (int c = 0; c < 64; ++c)
            acc2 = fmaf(sm.e.ein[row][c], sm.e.wef[c][lane], acc2);
        edge[(size_t)(g0 + row) * 64 + lane] = fmaxf(acc2, 0.f);
    }
    grid.sync();

    // ---------------- Layers: preload wT + e once, then 4 fused layers -----
    {
        const float* wsrc = top ? (wvuT + (size_t)b * 262144 + (size_t)i0 * 512)
                                : (wvu + (size_t)b * 262144 + (size_t)(i0 - 512) * 512);
        for (int t = tid; t < 2048; t += 256) {
            int r = t >> 9, j = t & 511;
            sm.l.wT[j][r] = wsrc[(size_t)r * 512 + j];
        }
        int r = tid >> 6, c = tid & 63;
        sm.l.e[r][c] = edge[(size_t)(g0 + r) * 64 + c];
    }
    const int f = tid & 63, q = tid >> 6;
    const float rnorm = 1.0f / normf[b * 1024 + i0 + q];

    for (int l = 0; l < 4; ++l) {
        const float* xin = (l & 1) ? x1buf : x0buf;
        float* xout = (l == 3) ? out : ((l & 1) ? x0buf : x1buf);
        const float* WmL = Wm + l * 8192;
        const float* WuL = Wu + l * 8192;

        sm.l.x[q][f] = xin[(size_t)(g0 + q) * 64 + f];
        __syncthreads();

        const float* xb = xin + ((size_t)b * 1024 + (top ? 512 : 0)) * 64 + f;
        float a0 = 0, a1 = 0, a2 = 0, a3 = 0;
#pragma unroll 4
        for (int jj = 0; jj < 128; ++jj) {
            int j = q * 128 + jj;
            float xv = xb[(size_t)j * 64];
            float4 w4 = *(const float4*)&sm.l.wT[j][0];
            a0 = fmaf(w4.x, xv, a0);
            a1 = fmaf(w4.y, xv, a1);
            a2 = fmaf(w4.z, xv, a2);
            a3 = fmaf(w4.w, xv, a3);
        }
        sm.l.part[q][0][f] = a0; sm.l.part[q][1][f] = a1;
        sm.l.part[q][2][f] = a2; sm.l.part[q][3][f] = a3;
        __syncthreads();
        float aggv = (sm.l.part[0][q][f] + sm.l.part[1][q][f] +
                      sm.l.part[2][q][f] + sm.l.part[3][q][f]) * rnorm;
        sm.l.agg[q][f] = aggv;
        __syncthreads();
        float mv = 0.f;
#pragma unroll 4
        for (int c = 0; c < 64; ++c) mv = fmaf(sm.l.agg[q][c], WmL[c * 64 + f], mv);
#pragma unroll 4
        for (int c = 0; c < 64; ++c) mv = fmaf(sm.l.e[q][c], WmL[(64 + c) * 64 + f], mv);
        mv = fmaxf(mv, 0.f);
        sm.l.msg[q][f] = mv;
        __syncthreads();
        float h = 0.f;
#pragma unroll 4
        for (int c = 0; c < 64; ++c) h = fmaf(sm.l.x[q][c], WuL[c * 64 + f], h);
#pragma unroll 4
        for (int c = 0; c < 64; ++c) h = fmaf(sm.l.msg[q][c], WuL[(64 + c) * 64 + f], h);
        if (l != 3) h = fmaxf(h, 0.f);
        xout[(size_t)(g0 + q) * 64 + f] = h;
        grid.sync();
    }
}

extern "C" void kernel_launch(void* const* d_in, const int* in_sizes, int n_in,
                              void* d_out, int out_size, void* d_ws, size_t ws_size,
                              hipStream_t stream) {
    const float* nf  = (const float*)d_in[0];
    const float* adj = (const float*)d_in[1];
    const float* wvu = (const float*)d_in[2];
    const float* Wi  = (const float*)d_in[3];
    const float* bi  = (const float*)d_in[4];
    const float* Wee = (const float*)d_in[5];
    const float* Wef = (const float*)d_in[6];
    const float* Wm  = (const float*)d_in[7];
    const float* Wu  = (const float*)d_in[8];
    float* out = (float*)d_out;
    float* ws = (float*)d_ws;

    float* wvuT     = ws;               // 524288 floats
    float* x0buf    = ws + 524288;      // 131072
    float* x1buf    = ws + 655360;      // 131072
    float* edge     = ws + 786432;      // 131072
    float* normf    = ws + 917504;      // 2048
    float* partials = ws + 919552;      // 131072
    int*   nmax     = (int*)(ws + 1050624);

    void* args[] = {
        (void*)&nf, (void*)&adj, (void*)&wvu, (void*)&Wi, (void*)&bi,
        (void*)&Wee, (void*)&Wef, (void*)&Wm, (void*)&Wu, (void*)&out,
        (void*)&wvuT, (void*)&x0buf, (void*)&x1buf, (void*)&edge,
        (void*)&normf, (void*)&partials, (void*)&nmax
    };
    hipLaunchCooperativeKernel((void*)k_all, dim3(512), dim3(256), args, 0, stream);
}

// Round 6
// 355.938 us; speedup vs baseline: 1.6801x; 1.6801x over previous
//
#include <hip/hip_runtime.h>

// Problem constants: B=2, N=1024, U=V=512, F_IN=1, F=64, L=4
#define NTOT 1024
#define HALF 512
#define NBLK 512

struct PrepS  { float tile[32][33]; };
struct EdgeS  { float adjr[4][1024]; float w[4][512]; float nfv[1024];
                float wef[64][64]; float ein[4][64]; };
struct LayerS { float wT[512][4]; float e[4][64]; float x[4][64];
                float part[4][4][64]; float agg[4][64]; float msg[4][64]; };
union SMem { PrepS p; EdgeS e; LayerS l; };

// one-shot global barrier; counters zeroed by memset before launch.
// Timeout cap: a residency failure degrades to wrong results, not a hang.
__device__ __forceinline__ void gbar(int* bars, int idx) {
    __syncthreads();
    if (threadIdx.x == 0) {
        int* c = bars + idx * 32;
        __threadfence();                       // release prior writes
        atomicAdd(c, 1);                       // device-scope by default
        int spins = 0;
        while (__hip_atomic_load(c, __ATOMIC_RELAXED, __HIP_MEMORY_SCOPE_AGENT) < NBLK
               && spins < (1 << 22)) {
            __builtin_amdgcn_s_sleep(2);
            ++spins;
        }
        __threadfence();                       // acquire
    }
    __syncthreads();
}

__global__ void __launch_bounds__(256, 2) k_all(
    const float* __restrict__ nf, const float* __restrict__ adj,
    const float* __restrict__ wvu, const float* __restrict__ Wi,
    const float* __restrict__ bi, const float* __restrict__ Wee,
    const float* __restrict__ Wef, const float* __restrict__ Wm,
    const float* __restrict__ Wu, float* __restrict__ out,
    float* __restrict__ wvuT, float* __restrict__ x0buf,
    float* __restrict__ x1buf, float* __restrict__ normf,
    int* __restrict__ bars)
{
    __shared__ SMem sm;
    __shared__ float snorm[4];
    __shared__ float swmax[4];
    const int bid = blockIdx.x, tid = threadIdx.x;
    const int g0 = bid * 4;
    const int b = g0 >> 10, i0 = g0 & 1023;
    const bool top = (i0 < 512);
    const int lane = tid & 63, wave = tid >> 6;

    // ---------- Phase A: norm colsums (exact atomicAdd) + transpose + x0 ----
    {
        int cb = bid >> 8, cc = (bid >> 6) & 3, rc = bid & 63;
        int col = cc * 256 + tid;
        const float* p = adj + (size_t)cb * NTOT * NTOT + (size_t)rc * 16 * NTOT + col;
        float s = 0.f;
#pragma unroll
        for (int r = 0; r < 16; ++r) s += 1.0f - p[(size_t)r * NTOT];
        atomicAdd(&normf[cb * NTOT + col], s);   // terms are exact integers
    }
    {
        int tb = bid >> 8, tyi = (bid >> 4) & 15, txi = bid & 15;
        int xb = txi * 32, yb = tyi * 32;
        const float* src = wvu + (size_t)tb * HALF * HALF;
        float* dst = wvuT + (size_t)tb * HALF * HALF;
        int tx = tid & 31, ty = tid >> 5; // 32 x 8
#pragma unroll
        for (int k = 0; k < 32; k += 8)
            sm.p.tile[ty + k][tx] = src[(size_t)(yb + ty + k) * HALF + xb + tx];
        __syncthreads();
#pragma unroll
        for (int k = 0; k < 32; k += 8)
            dst[(size_t)(xb + ty + k) * HALF + yb + tx] = sm.p.tile[tx][ty + k];
    }
    {
        int e = bid * 256 + tid;
        int f = e & 63, bn = e >> 6;
        x0buf[e] = fmaxf(fmaf(nf[bn], Wi[f], bi[f]), 0.f);
    }
    __syncthreads();   // tile reads done; union region reused for EdgeS below

    // ---------- stage EdgeS parts with no cross-block deps (hide under bar0)
    {
        const float4* src = (const float4*)(adj + (size_t)b * 1048576 + (size_t)i0 * 1024);
        float4* dst = (float4*)sm.e.adjr;
        for (int t = tid; t < 1024; t += 256) dst[t] = src[t];
        const float4* nsrc = (const float4*)(nf + b * 1024);
        ((float4*)sm.e.nfv)[tid] = nsrc[tid];
        const float4* wefs = (const float4*)Wef;
        float4* wefd = (float4*)sm.e.wef;
        for (int t = tid; t < 1024; t += 256) wefd[t] = wefs[t];
    }
    gbar(bars, 0);

    // ---------- post-bar0: stage w (needs wvuT), own norms, global max ------
    {
        const float* wsrc = top ? (wvuT + (size_t)b * 262144 + (size_t)i0 * 512)
                                : (wvu + (size_t)b * 262144 + (size_t)(i0 - 512) * 512);
        const float4* w4s = (const float4*)wsrc;
        float4* wds = (float4*)sm.e.w;
        for (int t = tid; t < 512; t += 256) wds[t] = w4s[t];
    }
    if (tid < 4) {
        snorm[tid] = fmaxf(normf[b * NTOT + i0 + tid], 1.0f);
    }
    {
        const float4* n4 = (const float4*)normf;
        float4 v0 = n4[tid * 2], v1 = n4[tid * 2 + 1];
        float m = 1.0f;
        m = fmaxf(m, fmaxf(fmaxf(v0.x, v0.y), fmaxf(v0.z, v0.w)));
        m = fmaxf(m, fmaxf(fmaxf(v1.x, v1.y), fmaxf(v1.z, v1.w)));
#pragma unroll
        for (int o = 32; o > 0; o >>= 1) m = fmaxf(m, __shfl_xor(m, o, 64));
        if (lane == 0) swmax[wave] = m;
    }
    __syncthreads();

    // ---------- Phase C: edge embedding (result kept in registers) ----------
    float eval;
    {
        int row = wave;
        int sameoff = top ? 0 : 512;
        int crossoff = top ? 512 : 0;
        float sp = 0.f, smv = 0.f;
#pragma unroll
        for (int it = 0; it < 8; ++it) {
            int j = sameoff + it * 64 + lane;
            float m = 1.0f - sm.e.adjr[row][j];
            float x = sm.e.nfv[j];
            sp = fmaf(m, fmaxf(x, 0.f), sp);
            smv = fmaf(m, fmaxf(-x, 0.f), smv);
        }
#pragma unroll
        for (int o = 32; o > 0; o >>= 1) {
            sp += __shfl_xor(sp, o, 64);
            smv += __shfl_xor(smv, o, 64);
        }
        float W0 = 0.f, W1 = 0.f;
        if (lane < 63) { W0 = Wee[lane]; W1 = Wee[63 + lane]; }
        float acc = fabsf(W1) * (W1 > 0.f ? sp : smv);
        const float* arow = &sm.e.adjr[row][crossoff];
        const float* nrow = &sm.e.nfv[crossoff];
        const float* wrow = &sm.e.w[row][0];
#pragma unroll 4
        for (int qq = 0; qq < 128; ++qq) {
            float4 a4 = *(const float4*)(arow + qq * 4);
            float4 w4 = *(const float4*)(wrow + qq * 4);
            float4 n4 = *(const float4*)(nrow + qq * 4);
            float c;
            c = fmaxf(fmaf(w4.x, W0, n4.x * W1), 0.f); acc = fmaf(1.0f - a4.x, c, acc);
            c = fmaxf(fmaf(w4.y, W0, n4.y * W1), 0.f); acc = fmaf(1.0f - a4.y, c, acc);
            c = fmaxf(fmaf(w4.z, W0, n4.z * W1), 0.f); acc = fmaf(1.0f - a4.z, c, acc);
            c = fmaxf(fmaf(w4.w, W0, n4.w * W1), 0.f); acc = fmaf(1.0f - a4.w, c, acc);
        }
        float nv = snorm[row];
        float nmaxv = fmaxf(fmaxf(swmax[0], swmax[1]), fmaxf(swmax[2], swmax[3]));
        float ein = (lane < 63) ? (acc * (1.0f / nv)) : (nv / nmaxv);
        sm.e.ein[row][lane] = ein;
        __syncthreads();
        float acc2 = 0.f;
#pragma unroll
        for (int c = 0; c < 64; ++c)
            acc2 = fmaf(sm.e.ein[row][c], sm.e.wef[c][lane], acc2);
        eval = fmaxf(acc2, 0.f);
    }
    __syncthreads();   // EdgeS reads done; union switches to LayerS

    // ---------- Layers: e in LDS from regs, wT staged once ------------------
    const int f = lane, q = wave;
    sm.l.e[q][f] = eval;
    {
        const float* wsrc = top ? (wvuT + (size_t)b * 262144 + (size_t)i0 * 512)
                                : (wvu + (size_t)b * 262144 + (size_t)(i0 - 512) * 512);
        for (int t = tid; t < 2048; t += 256) {
            int r = t >> 9, j = t & 511;
            sm.l.wT[j][r] = wsrc[(size_t)r * 512 + j];
        }
    }
    const float rnorm = 1.0f / snorm[q];

    for (int l = 0; l < 4; ++l) {
        const float* xin = (l & 1) ? x1buf : x0buf;
        float* xout = (l == 3) ? out : ((l & 1) ? x0buf : x1buf);
        const float* WmL = Wm + l * 8192;
        const float* WuL = Wu + l * 8192;

        sm.l.x[q][f] = xin[(size_t)(g0 + q) * 64 + f];
        __syncthreads();

        const float* xb = xin + ((size_t)b * 1024 + (top ? 512 : 0)) * 64 + f;
        float a0 = 0, a1 = 0, a2 = 0, a3 = 0;
#pragma unroll 4
        for (int jj = 0; jj < 128; ++jj) {
            int j = q * 128 + jj;
            float xv = xb[(size_t)j * 64];
            float4 w4 = *(const float4*)&sm.l.wT[j][0];
            a0 = fmaf(w4.x, xv, a0);
            a1 = fmaf(w4.y, xv, a1);
            a2 = fmaf(w4.z, xv, a2);
            a3 = fmaf(w4.w, xv, a3);
        }
        sm.l.part[q][0][f] = a0; sm.l.part[q][1][f] = a1;
        sm.l.part[q][2][f] = a2; sm.l.part[q][3][f] = a3;
        __syncthreads();
        float aggv = (sm.l.part[0][q][f] + sm.l.part[1][q][f] +
                      sm.l.part[2][q][f] + sm.l.part[3][q][f]) * rnorm;
        sm.l.agg[q][f] = aggv;
        __syncthreads();
        float mv = 0.f;
#pragma unroll 4
        for (int c = 0; c < 64; ++c) mv = fmaf(sm.l.agg[q][c], WmL[c * 64 + f], mv);
#pragma unroll 4
        for (int c = 0; c < 64; ++c) mv = fmaf(sm.l.e[q][c], WmL[(64 + c) * 64 + f], mv);
        mv = fmaxf(mv, 0.f);
        sm.l.msg[q][f] = mv;
        __syncthreads();
        float h = 0.f;
#pragma unroll 4
        for (int c = 0; c < 64; ++c) h = fmaf(sm.l.x[q][c], WuL[c * 64 + f], h);
#pragma unroll 4
        for (int c = 0; c < 64; ++c) h = fmaf(sm.l.msg[q][c], WuL[(64 + c) * 64 + f], h);
        if (l != 3) h = fmaxf(h, 0.f);
        xout[(size_t)(g0 + q) * 64 + f] = h;
        if (l != 3) gbar(bars, 1 + l);
    }
}

extern "C" void kernel_launch(void* const* d_in, const int* in_sizes, int n_in,
                              void* d_out, int out_size, void* d_ws, size_t ws_size,
                              hipStream_t stream) {
    const float* nf  = (const float*)d_in[0];
    const float* adj = (const float*)d_in[1];
    const float* wvu = (const float*)d_in[2];
    const float* Wi  = (const float*)d_in[3];
    const float* bi  = (const float*)d_in[4];
    const float* Wee = (const float*)d_in[5];
    const float* Wef = (const float*)d_in[6];
    const float* Wm  = (const float*)d_in[7];
    const float* Wu  = (const float*)d_in[8];
    float* out = (float*)d_out;
    float* ws = (float*)d_ws;

    float* wvuT  = ws;               // 524288 floats
    float* x0buf = ws + 524288;      // 131072
    float* x1buf = ws + 655360;      // 131072
    float* ctrl  = ws + 786432;      // normf[2048] + bars[4*32]
    float* normf = ctrl;
    int*   bars  = (int*)(ctrl + 2048);

    hipMemsetAsync(ctrl, 0, (2048 + 128) * sizeof(float), stream);

    k_all<<<NBLK, 256, 0, stream>>>(nf, adj, wvu, Wi, bi, Wee, Wef, Wm, Wu,
                                    out, wvuT, x0buf, x1buf, normf, bars);
}

// Round 8
// 270.734 us; speedup vs baseline: 2.2088x; 1.3147x over previous
//
#include <hip/hip_runtime.h>

// Problem constants: B=2, N=1024, U=V=512, F_IN=1, F=64, L=4
#define NTOT 1024
#define HALF 512
#define NBLK 512

struct PrepS  { float tile[32][33]; };
struct EdgeS  { float adjr[4][1024]; float w[4][512]; float nfv[1024];
                float wef[64][64]; float ein[4][64]; };
struct LayerS { float wT[512][4]; float e[4][64]; float x[4][64];
                float part[4][4][64]; float agg[4][64]; float msg[4][64]; };
union SMem { PrepS p; EdgeS e; LayerS l; };

// Contention-free one-shot barrier: per-block flag stores (no RMW),
// block 0 checks all flags cooperatively and broadcasts `done`.
// Timeout caps: a residency failure degrades to wrong results, not a hang.
__device__ __forceinline__ void gbar(int* flags, int* done, int idx) {
    const int bid = blockIdx.x, tid = threadIdx.x;
    __syncthreads();
    if (tid == 0) {
        __threadfence();                      // release prior writes
        __hip_atomic_store(&flags[idx * NBLK + bid], 1,
                           __ATOMIC_RELAXED, __HIP_MEMORY_SCOPE_AGENT);
    }
    if (bid == 0) {
        int* base = flags + idx * NBLK;
        int spins = 0;
        for (;;) {
            int v0 = __hip_atomic_load(&base[tid], __ATOMIC_RELAXED,
                                       __HIP_MEMORY_SCOPE_AGENT);
            int v1 = __hip_atomic_load(&base[256 + tid], __ATOMIC_RELAXED,
                                       __HIP_MEMORY_SCOPE_AGENT);
            if (__syncthreads_and(v0 & v1)) break;
            if (++spins > (1 << 20)) break;
            __builtin_amdgcn_s_sleep(4);
        }
        if (tid == 0) {
            __threadfence();
            __hip_atomic_store(&done[idx], 1, __ATOMIC_RELAXED,
                               __HIP_MEMORY_SCOPE_AGENT);
        }
        __threadfence();                      // acquire for own reads
        __syncthreads();
    } else {
        if (tid == 0) {
            int spins = 0;
            while (__hip_atomic_load(&done[idx], __ATOMIC_RELAXED,
                                     __HIP_MEMORY_SCOPE_AGENT) == 0
                   && spins < (1 << 22)) {
                __builtin_amdgcn_s_sleep(10);
                ++spins;
            }
            __threadfence();                  // acquire
        }
        __syncthreads();
    }
}

__global__ void __launch_bounds__(256, 2) k_all(
    const float* __restrict__ nf, const float* __restrict__ adj,
    const float* __restrict__ wvu, const float* __restrict__ Wi,
    const float* __restrict__ bi, const float* __restrict__ Wee,
    const float* __restrict__ Wef, const float* __restrict__ Wm,
    const float* __restrict__ Wu, float* __restrict__ out,
    float* __restrict__ wvuT, float* __restrict__ x0buf,
    float* __restrict__ x1buf, float* __restrict__ normf,
    int* __restrict__ flags, int* __restrict__ done)
{
    __shared__ SMem sm;
    __shared__ float snorm[4];
    __shared__ float swmax[4];
    const int bid = blockIdx.x, tid = threadIdx.x;
    const int g0 = bid * 4;
    const int b = g0 >> 10, i0 = g0 & 1023;
    const bool top = (i0 < 512);
    const int lane = tid & 63, wave = tid >> 6;

    // ---------- Phase A: norm colsums (exact atomicAdd) + transpose + x0 ----
    {
        int cb = bid >> 8, cc = (bid >> 6) & 3, rc = bid & 63;
        int col = cc * 256 + tid;
        const float* p = adj + (size_t)cb * NTOT * NTOT + (size_t)rc * 16 * NTOT + col;
        float s = 0.f;
#pragma unroll
        for (int r = 0; r < 16; ++r) s += 1.0f - p[(size_t)r * NTOT];
        atomicAdd(&normf[cb * NTOT + col], s);   // terms are exact integers
    }
    {
        int tb = bid >> 8, tyi = (bid >> 4) & 15, txi = bid & 15;
        int xb = txi * 32, yb = tyi * 32;
        const float* src = wvu + (size_t)tb * HALF * HALF;
        float* dst = wvuT + (size_t)tb * HALF * HALF;
        int tx = tid & 31, ty = tid >> 5; // 32 x 8
#pragma unroll
        for (int k = 0; k < 32; k += 8)
            sm.p.tile[ty + k][tx] = src[(size_t)(yb + ty + k) * HALF + xb + tx];
        __syncthreads();
#pragma unroll
        for (int k = 0; k < 32; k += 8)
            dst[(size_t)(xb + ty + k) * HALF + yb + tx] = sm.p.tile[tx][ty + k];
    }
    {
        int e = bid * 256 + tid;
        int f = e & 63, bn = e >> 6;
        x0buf[e] = fmaxf(fmaf(nf[bn], Wi[f], bi[f]), 0.f);
    }
    __syncthreads();   // tile reads done; union region reused for EdgeS below

    // ---------- stage EdgeS parts with no cross-block deps (hide under bar0)
    {
        const float4* src = (const float4*)(adj + (size_t)b * 1048576 + (size_t)i0 * 1024);
        float4* dst = (float4*)sm.e.adjr;
        for (int t = tid; t < 1024; t += 256) dst[t] = src[t];
        const float4* nsrc = (const float4*)(nf + b * 1024);
        ((float4*)sm.e.nfv)[tid] = nsrc[tid];
        const float4* wefs = (const float4*)Wef;
        float4* wefd = (float4*)sm.e.wef;
        for (int t = tid; t < 1024; t += 256) wefd[t] = wefs[t];
    }
    gbar(flags, done, 0);

    // ---------- post-bar0: stage w (needs wvuT), own norms, global max ------
    {
        const float* wsrc = top ? (wvuT + (size_t)b * 262144 + (size_t)i0 * 512)
                                : (wvu + (size_t)b * 262144 + (size_t)(i0 - 512) * 512);
        const float4* w4s = (const float4*)wsrc;
        float4* wds = (float4*)sm.e.w;
        for (int t = tid; t < 512; t += 256) wds[t] = w4s[t];
    }
    if (tid < 4) {
        snorm[tid] = fmaxf(normf[b * NTOT + i0 + tid], 1.0f);
    }
    {
        const float4* n4 = (const float4*)normf;
        float4 v0 = n4[tid * 2], v1 = n4[tid * 2 + 1];
        float m = 1.0f;
        m = fmaxf(m, fmaxf(fmaxf(v0.x, v0.y), fmaxf(v0.z, v0.w)));
        m = fmaxf(m, fmaxf(fmaxf(v1.x, v1.y), fmaxf(v1.z, v1.w)));
#pragma unroll
        for (int o = 32; o > 0; o >>= 1) m = fmaxf(m, __shfl_xor(m, o, 64));
        if (lane == 0) swmax[wave] = m;
    }
    __syncthreads();

    // ---------- Phase C: edge embedding (result kept in registers) ----------
    float eval;
    {
        int row = wave;
        int sameoff = top ? 0 : 512;
        int crossoff = top ? 512 : 0;
        float sp = 0.f, smv = 0.f;
#pragma unroll
        for (int it = 0; it < 8; ++it) {
            int j = sameoff + it * 64 + lane;
            float m = 1.0f - sm.e.adjr[row][j];
            float x = sm.e.nfv[j];
            sp = fmaf(m, fmaxf(x, 0.f), sp);
            smv = fmaf(m, fmaxf(-x, 0.f), smv);
        }
#pragma unroll
        for (int o = 32; o > 0; o >>= 1) {
            sp += __shfl_xor(sp, o, 64);
            smv += __shfl_xor(smv, o, 64);
        }
        float W0 = 0.f, W1 = 0.f;
        if (lane < 63) { W0 = Wee[lane]; W1 = Wee[63 + lane]; }
        float acc = fabsf(W1) * (W1 > 0.f ? sp : smv);
        const float* arow = &sm.e.adjr[row][crossoff];
        const float* nrow = &sm.e.nfv[crossoff];
        const float* wrow = &sm.e.w[row][0];
#pragma unroll 4
        for (int qq = 0; qq < 128; ++qq) {
            float4 a4 = *(const float4*)(arow + qq * 4);
            float4 w4 = *(const float4*)(wrow + qq * 4);
            float4 n4 = *(const float4*)(nrow + qq * 4);
            float c;
            c = fmaxf(fmaf(w4.x, W0, n4.x * W1), 0.f); acc = fmaf(1.0f - a4.x, c, acc);
            c = fmaxf(fmaf(w4.y, W0, n4.y * W1), 0.f); acc = fmaf(1.0f - a4.y, c, acc);
            c = fmaxf(fmaf(w4.z, W0, n4.z * W1), 0.f); acc = fmaf(1.0f - a4.z, c, acc);
            c = fmaxf(fmaf(w4.w, W0, n4.w * W1), 0.f); acc = fmaf(1.0f - a4.w, c, acc);
        }
        float nv = snorm[row];
        float nmaxv = fmaxf(fmaxf(swmax[0], swmax[1]), fmaxf(swmax[2], swmax[3]));
        float ein = (lane < 63) ? (acc * (1.0f / nv)) : (nv / nmaxv);
        sm.e.ein[row][lane] = ein;
        __syncthreads();
        float acc2 = 0.f;
#pragma unroll
        for (int c = 0; c < 64; ++c)
            acc2 = fmaf(sm.e.ein[row][c], sm.e.wef[c][lane], acc2);
        eval = fmaxf(acc2, 0.f);
    }
    __syncthreads();   // EdgeS reads done; union switches to LayerS

    // ---------- Layers: e in LDS from regs, wT staged once ------------------
    const int f = lane, q = wave;
    sm.l.e[q][f] = eval;
    {
        const float* wsrc = top ? (wvuT + (size_t)b * 262144 + (size_t)i0 * 512)
                                : (wvu + (size_t)b * 262144 + (size_t)(i0 - 512) * 512);
        for (int t = tid; t < 2048; t += 256) {
            int r = t >> 9, j = t & 511;
            sm.l.wT[j][r] = wsrc[(size_t)r * 512 + j];
        }
    }
    const float rnorm = 1.0f / snorm[q];

    for (int l = 0; l < 4; ++l) {
        const float* xin = (l & 1) ? x1buf : x0buf;
        float* xout = (l == 3) ? out : ((l & 1) ? x0buf : x1buf);
        const float* WmL = Wm + l * 8192;
        const float* WuL = Wu + l * 8192;

        sm.l.x[q][f] = xin[(size_t)(g0 + q) * 64 + f];
        __syncthreads();

        const float* xb = xin + ((size_t)b * 1024 + (top ? 512 : 0)) * 64 + f;
        float a0 = 0, a1 = 0, a2 = 0, a3 = 0;
#pragma unroll 4
        for (int jj = 0; jj < 128; ++jj) {
            int j = q * 128 + jj;
            float xv = xb[(size_t)j * 64];
            float4 w4 = *(const float4*)&sm.l.wT[j][0];
            a0 = fmaf(w4.x, xv, a0);
            a1 = fmaf(w4.y, xv, a1);
            a2 = fmaf(w4.z, xv, a2);
            a3 = fmaf(w4.w, xv, a3);
        }
        sm.l.part[q][0][f] = a0; sm.l.part[q][1][f] = a1;
        sm.l.part[q][2][f] = a2; sm.l.part[q][3][f] = a3;
        __syncthreads();
        float aggv = (sm.l.part[0][q][f] + sm.l.part[1][q][f] +
                      sm.l.part[2][q][f] + sm.l.part[3][q][f]) * rnorm;
        sm.l.agg[q][f] = aggv;
        __syncthreads();
        float mv = 0.f;
#pragma unroll 4
        for (int c = 0; c < 64; ++c) mv = fmaf(sm.l.agg[q][c], WmL[c * 64 + f], mv);
#pragma unroll 4
        for (int c = 0; c < 64; ++c) mv = fmaf(sm.l.e[q][c], WmL[(64 + c) * 64 + f], mv);
        mv = fmaxf(mv, 0.f);
        sm.l.msg[q][f] = mv;
        __syncthreads();
        float h = 0.f;
#pragma unroll 4
        for (int c = 0; c < 64; ++c) h = fmaf(sm.l.x[q][c], WuL[c * 64 + f], h);
#pragma unroll 4
        for (int c = 0; c < 64; ++c) h = fmaf(sm.l.msg[q][c], WuL[(64 + c) * 64 + f], h);
        if (l != 3) h = fmaxf(h, 0.f);
        xout[(size_t)(g0 + q) * 64 + f] = h;
        if (l != 3) gbar(flags, done, 1 + l);
    }
}

extern "C" void kernel_launch(void* const* d_in, const int* in_sizes, int n_in,
                              void* d_out, int out_size, void* d_ws, size_t ws_size,
                              hipStream_t stream) {
    const float* nf  = (const float*)d_in[0];
    const float* adj = (const float*)d_in[1];
    const float* wvu = (const float*)d_in[2];
    const float* Wi  = (const float*)d_in[3];
    const float* bi  = (const float*)d_in[4];
    const float* Wee = (const float*)d_in[5];
    const float* Wef = (const float*)d_in[6];
    const float* Wm  = (const float*)d_in[7];
    const float* Wu  = (const float*)d_in[8];
    float* out = (float*)d_out;
    float* ws = (float*)d_ws;

    float* wvuT  = ws;               // 524288 floats
    float* x0buf = ws + 524288;      // 131072
    float* x1buf = ws + 655360;      // 131072
    float* ctrl  = ws + 786432;      // normf[2048] + flags[4*512] + done[4]
    float* normf = ctrl;
    int*   flags = (int*)(ctrl + 2048);
    int*   done  = (int*)(ctrl + 2048 + 4 * NBLK);

    hipMemsetAsync(ctrl, 0, (2048 + 4 * NBLK + 4) * sizeof(float), stream);

    k_all<<<NBLK, 256, 0, stream>>>(nf, adj, wvu, Wi, bi, Wee, Wef, Wm, Wu,
                                    out, wvuT, x0buf, x1buf, normf, flags, done);
}

// Round 9
// 190.968 us; speedup vs baseline: 3.1314x; 1.4177x over previous
//
#include <hip/hip_runtime.h>

// Problem constants: B=2, N=1024, U=V=512, F_IN=1, F=64, L=4
#define NTOT 1024
#define HALF 512
#define NBLK 512

struct PrepS  { float tile[32][33]; };
struct EdgeS  { float adjr[4][1024]; float w[4][512]; float nfv[1024];
                float wef[64][64]; float ein[4][64]; };
struct LayerS { float wT[512][4]; float e[4][64]; float x[4][64];
                float part[4][4][64]; float agg[4][64]; float msg[4][64]; };
union SMem { PrepS p; EdgeS e; LayerS l; };

// Coherent (agent-scope, relaxed) element accesses: compile to global ops with
// sc0/sc1 bits -> write-through / cache-bypass at the XCD-coherence point.
// No threadfence (wbl2/inv) needed anywhere.
__device__ __forceinline__ void st_coh(float* p, float v) {
    __hip_atomic_store(p, v, __ATOMIC_RELAXED, __HIP_MEMORY_SCOPE_AGENT);
}
__device__ __forceinline__ float ld_coh(const float* p) {
    return __hip_atomic_load((float*)p, __ATOMIC_RELAXED, __HIP_MEMORY_SCOPE_AGENT);
}

// Fence-free barrier: every wave drains its own (coherent) stores with
// vmcnt(0), then one flag store per block; block 0 polls all flags and
// broadcasts `done`. Timeouts degrade residency failure to wrong results.
__device__ __forceinline__ void gbar(int* flags, int* done, int idx) {
    asm volatile("s_waitcnt vmcnt(0) lgkmcnt(0)" ::: "memory");
    __syncthreads();
    const int bid = blockIdx.x, tid = threadIdx.x;
    if (bid == 0) {
        if (tid == 0)
            __hip_atomic_store(&flags[idx * NBLK], 1,
                               __ATOMIC_RELAXED, __HIP_MEMORY_SCOPE_AGENT);
        int* base = flags + idx * NBLK;
        int spins = 0;
        for (;;) {
            int v0 = __hip_atomic_load(&base[tid], __ATOMIC_RELAXED,
                                       __HIP_MEMORY_SCOPE_AGENT);
            int v1 = __hip_atomic_load(&base[256 + tid], __ATOMIC_RELAXED,
                                       __HIP_MEMORY_SCOPE_AGENT);
            if (__syncthreads_and(v0 & v1)) break;
            if (++spins > (1 << 20)) break;
            __builtin_amdgcn_s_sleep(2);
        }
        if (tid == 0)
            __hip_atomic_store(&done[idx], 1, __ATOMIC_RELAXED,
                               __HIP_MEMORY_SCOPE_AGENT);
        __syncthreads();
    } else {
        if (tid == 0) {
            __hip_atomic_store(&flags[idx * NBLK + bid], 1,
                               __ATOMIC_RELAXED, __HIP_MEMORY_SCOPE_AGENT);
            int spins = 0;
            while (__hip_atomic_load(&done[idx], __ATOMIC_RELAXED,
                                     __HIP_MEMORY_SCOPE_AGENT) == 0
                   && spins < (1 << 22)) {
                __builtin_amdgcn_s_sleep(4);
                ++spins;
            }
        }
        __syncthreads();
    }
}

__global__ void __launch_bounds__(256, 2) k_all(
    const float* __restrict__ nf, const float* __restrict__ adj,
    const float* __restrict__ wvu, const float* __restrict__ Wi,
    const float* __restrict__ bi, const float* __restrict__ Wee,
    const float* __restrict__ Wef, const float* __restrict__ Wm,
    const float* __restrict__ Wu, float* __restrict__ out,
    float* __restrict__ wvuT, float* __restrict__ x0buf,
    float* __restrict__ x1buf, float* __restrict__ normf,
    int* __restrict__ flags, int* __restrict__ done)
{
    __shared__ SMem sm;
    __shared__ float snorm[4];
    __shared__ float swmax[4];
    const int bid = blockIdx.x, tid = threadIdx.x;
    const int g0 = bid * 4;
    const int b = g0 >> 10, i0 = g0 & 1023;
    const bool top = (i0 < 512);
    const int lane = tid & 63, wave = tid >> 6;

    // ---------- Phase A: norm colsums (atomicAdd, exact) + transpose + x0 ---
    {
        int cb = bid >> 8, cc = (bid >> 6) & 3, rc = bid & 63;
        int col = cc * 256 + tid;
        const float* p = adj + (size_t)cb * NTOT * NTOT + (size_t)rc * 16 * NTOT + col;
        float s = 0.f;
#pragma unroll
        for (int r = 0; r < 16; ++r) s += 1.0f - p[(size_t)r * NTOT];
        atomicAdd(&normf[cb * NTOT + col], s);   // RMW at coherence point
    }
    {
        int tb = bid >> 8, tyi = (bid >> 4) & 15, txi = bid & 15;
        int xb = txi * 32, yb = tyi * 32;
        const float* src = wvu + (size_t)tb * HALF * HALF;
        float* dst = wvuT + (size_t)tb * HALF * HALF;
        int tx = tid & 31, ty = tid >> 5; // 32 x 8
#pragma unroll
        for (int k = 0; k < 32; k += 8)
            sm.p.tile[ty + k][tx] = src[(size_t)(yb + ty + k) * HALF + xb + tx];
        __syncthreads();
#pragma unroll
        for (int k = 0; k < 32; k += 8)
            st_coh(&dst[(size_t)(xb + ty + k) * HALF + yb + tx], sm.p.tile[tx][ty + k]);
    }
    float xreg;   // own x[g0+q][f] kept in register across layers
    {
        int e = bid * 256 + tid;        // == (g0+q)*64 + f
        int f0 = e & 63, bn = e >> 6;
        xreg = fmaxf(fmaf(nf[bn], Wi[f0], bi[f0]), 0.f);
        st_coh(&x0buf[e], xreg);
    }
    __syncthreads();   // tile reads done; union switches to EdgeS

    // ---------- stage EdgeS parts with no cross-block deps (hide under bar0)
    {
        const float4* src = (const float4*)(adj + (size_t)b * 1048576 + (size_t)i0 * 1024);
        float4* dst = (float4*)sm.e.adjr;
        for (int t = tid; t < 1024; t += 256) dst[t] = src[t];
        const float4* nsrc = (const float4*)(nf + b * 1024);
        ((float4*)sm.e.nfv)[tid] = nsrc[tid];
        const float4* wefs = (const float4*)Wef;
        float4* wefd = (float4*)sm.e.wef;
        for (int t = tid; t < 1024; t += 256) wefd[t] = wefs[t];
    }
    gbar(flags, done, 0);

    // ---------- post-bar0: stage w, own norms, global max -------------------
    {
        if (top) {
            const float* wsrc = wvuT + (size_t)b * 262144 + (size_t)i0 * 512;
            float* wflat = (float*)sm.e.w;
            for (int t = tid; t < 2048; t += 256) wflat[t] = ld_coh(&wsrc[t]);
        } else {
            const float* wsrc = wvu + (size_t)b * 262144 + (size_t)(i0 - 512) * 512;
            const float4* w4s = (const float4*)wsrc;
            float4* wds = (float4*)sm.e.w;
            for (int t = tid; t < 512; t += 256) wds[t] = w4s[t];
        }
    }
    if (tid < 4) snorm[tid] = fmaxf(ld_coh(&normf[b * NTOT + i0 + tid]), 1.0f);
    {
        float m = 1.0f;
#pragma unroll
        for (int u = 0; u < 8; ++u)
            m = fmaxf(m, ld_coh(&normf[tid * 8 + u]));
#pragma unroll
        for (int o = 32; o > 0; o >>= 1) m = fmaxf(m, __shfl_xor(m, o, 64));
        if (lane == 0) swmax[wave] = m;
    }
    __syncthreads();

    // ---------- Phase C: edge embedding (result kept in registers) ----------
    float eval;
    {
        int row = wave;
        int sameoff = top ? 0 : 512;
        int crossoff = top ? 512 : 0;
        float sp = 0.f, smv = 0.f;
#pragma unroll
        for (int it = 0; it < 8; ++it) {
            int j = sameoff + it * 64 + lane;
            float m = 1.0f - sm.e.adjr[row][j];
            float x = sm.e.nfv[j];
            sp = fmaf(m, fmaxf(x, 0.f), sp);
            smv = fmaf(m, fmaxf(-x, 0.f), smv);
        }
#pragma unroll
        for (int o = 32; o > 0; o >>= 1) {
            sp += __shfl_xor(sp, o, 64);
            smv += __shfl_xor(smv, o, 64);
        }
        float W0 = 0.f, W1 = 0.f;
        if (lane < 63) { W0 = Wee[lane]; W1 = Wee[63 + lane]; }
        float acc = fabsf(W1) * (W1 > 0.f ? sp : smv);
        const float* arow = &sm.e.adjr[row][crossoff];
        const float* nrow = &sm.e.nfv[crossoff];
        const float* wrow = &sm.e.w[row][0];
#pragma unroll 4
        for (int qq = 0; qq < 128; ++qq) {
            float4 a4 = *(const float4*)(arow + qq * 4);
            float4 w4 = *(const float4*)(wrow + qq * 4);
            float4 n4 = *(const float4*)(nrow + qq * 4);
            float c;
            c = fmaxf(fmaf(w4.x, W0, n4.x * W1), 0.f); acc = fmaf(1.0f - a4.x, c, acc);
            c = fmaxf(fmaf(w4.y, W0, n4.y * W1), 0.f); acc = fmaf(1.0f - a4.y, c, acc);
            c = fmaxf(fmaf(w4.z, W0, n4.z * W1), 0.f); acc = fmaf(1.0f - a4.z, c, acc);
            c = fmaxf(fmaf(w4.w, W0, n4.w * W1), 0.f); acc = fmaf(1.0f - a4.w, c, acc);
        }
        float nv = snorm[row];
        float nmaxv = fmaxf(fmaxf(swmax[0], swmax[1]), fmaxf(swmax[2], swmax[3]));
        float ein = (lane < 63) ? (acc * (1.0f / nv)) : (nv / nmaxv);
        sm.e.ein[row][lane] = ein;
        __syncthreads();
        float acc2 = 0.f;
#pragma unroll
        for (int c = 0; c < 64; ++c)
            acc2 = fmaf(sm.e.ein[row][c], sm.e.wef[c][lane], acc2);
        eval = fmaxf(acc2, 0.f);
    }
    __syncthreads();   // EdgeS reads done; union switches to LayerS

    // ---------- Layers: e + own-x in regs, wT staged once -------------------
    const int f = lane, q = wave;
    sm.l.e[q][f] = eval;
    {
        if (top) {
            const float* wsrc = wvuT + (size_t)b * 262144 + (size_t)i0 * 512;
            for (int t = tid; t < 2048; t += 256) {
                int r = t >> 9, j = t & 511;
                sm.l.wT[j][r] = ld_coh(&wsrc[r * 512 + j]);
            }
        } else {
            const float* wsrc = wvu + (size_t)b * 262144 + (size_t)(i0 - 512) * 512;
            for (int t = tid; t < 2048; t += 256) {
                int r = t >> 9, j = t & 511;
                sm.l.wT[j][r] = wsrc[r * 512 + j];
            }
        }
    }
    const float rnorm = 1.0f / snorm[q];

    for (int l = 0; l < 4; ++l) {
        const float* xin = (l & 1) ? x1buf : x0buf;
        float* xout = (l == 3) ? out : ((l & 1) ? x0buf : x1buf);
        const float* WmL = Wm + l * 8192;
        const float* WuL = Wu + l * 8192;

        sm.l.x[q][f] = xreg;            // own row from register, no reload
        __syncthreads();

        const float* xb = xin + ((size_t)b * 1024 + (top ? 512 : 0)) * 64 + f;
        float a0 = 0, a1 = 0, a2 = 0, a3 = 0;
#pragma unroll
        for (int jo = 0; jo < 128; jo += 32) {
            float xv[32];
#pragma unroll
            for (int u = 0; u < 32; ++u)
                xv[u] = ld_coh(xb + (size_t)(q * 128 + jo + u) * 64);
#pragma unroll
            for (int u = 0; u < 32; ++u) {
                int j = q * 128 + jo + u;
                float4 w4 = *(const float4*)&sm.l.wT[j][0];
                a0 = fmaf(w4.x, xv[u], a0);
                a1 = fmaf(w4.y, xv[u], a1);
                a2 = fmaf(w4.z, xv[u], a2);
                a3 = fmaf(w4.w, xv[u], a3);
            }
        }
        sm.l.part[q][0][f] = a0; sm.l.part[q][1][f] = a1;
        sm.l.part[q][2][f] = a2; sm.l.part[q][3][f] = a3;
        __syncthreads();
        float aggv = (sm.l.part[0][q][f] + sm.l.part[1][q][f] +
                      sm.l.part[2][q][f] + sm.l.part[3][q][f]) * rnorm;
        sm.l.agg[q][f] = aggv;
        __syncthreads();
        float mv = 0.f;
#pragma unroll 4
        for (int c = 0; c < 64; ++c) mv = fmaf(sm.l.agg[q][c], WmL[c * 64 + f], mv);
#pragma unroll 4
        for (int c = 0; c < 64; ++c) mv = fmaf(sm.l.e[q][c], WmL[(64 + c) * 64 + f], mv);
        mv = fmaxf(mv, 0.f);
        sm.l.msg[q][f] = mv;
        __syncthreads();
        float h = 0.f;
#pragma unroll 4
        for (int c = 0; c < 64; ++c) h = fmaf(sm.l.x[q][c], WuL[c * 64 + f], h);
#pragma unroll 4
        for (int c = 0; c < 64; ++c) h = fmaf(sm.l.msg[q][c], WuL[(64 + c) * 64 + f], h);
        if (l != 3) {
            h = fmaxf(h, 0.f);
            st_coh(&xout[(size_t)(g0 + q) * 64 + f], h);
            xreg = h;
            gbar(flags, done, 1 + l);
        } else {
            xout[(size_t)(g0 + q) * 64 + f] = h;   // final: normal store
        }
    }
}

extern "C" void kernel_launch(void* const* d_in, const int* in_sizes, int n_in,
                              void* d_out, int out_size, void* d_ws, size_t ws_size,
                              hipStream_t stream) {
    const float* nf  = (const float*)d_in[0];
    const float* adj = (const float*)d_in[1];
    const float* wvu = (const float*)d_in[2];
    const float* Wi  = (const float*)d_in[3];
    const float* bi  = (const float*)d_in[4];
    const float* Wee = (const float*)d_in[5];
    const float* Wef = (const float*)d_in[6];
    const float* Wm  = (const float*)d_in[7];
    const float* Wu  = (const float*)d_in[8];
    float* out = (float*)d_out;
    float* ws = (float*)d_ws;

    float* wvuT  = ws;               // 524288 floats
    float* x0buf = ws + 524288;      // 131072
    float* x1buf = ws + 655360;      // 131072
    float* ctrl  = ws + 786432;      // normf[2048] + flags[4*512] + done[4]
    float* normf = ctrl;
    int*   flags = (int*)(ctrl + 2048);
    int*   done  = (int*)(ctrl + 2048 + 4 * NBLK);

    hipMemsetAsync(ctrl, 0, (2048 + 4 * NBLK + 4) * sizeof(float), stream);

    k_all<<<NBLK, 256, 0, stream>>>(nf, adj, wvu, Wi, bi, Wee, Wef, Wm, Wu,
                                    out, wvuT, x0buf, x1buf, normf, flags, done);
}

// Round 10
// 187.885 us; speedup vs baseline: 3.1828x; 1.0164x over previous
//
#include <hip/hip_runtime.h>

// Problem constants: B=2, N=1024, U=V=512, F_IN=1, F=64, L=4
#define NTOT 1024
#define HALF 512
#define NBLK 512

struct EdgeS  { float adjr[4][1024]; float w[4][512]; float nfv[1024];
                float wef[64][64]; float ein[4][64]; };
struct LayerS { float e[4][64]; float x[4][64];
                float part[4][4][64]; float agg[4][64]; float msg[4][64]; };
union SMem { EdgeS e; LayerS l; };

__device__ __forceinline__ void st_coh(float* p, float v) {
    __hip_atomic_store(p, v, __ATOMIC_RELAXED, __HIP_MEMORY_SCOPE_AGENT);
}
__device__ __forceinline__ float ld_coh(const float* p) {
    return __hip_atomic_load((float*)p, __ATOMIC_RELAXED, __HIP_MEMORY_SCOPE_AGENT);
}

// Fence-free barrier, hierarchical wake: per-block flag stores (distinct
// addresses), block 0 polls all 512 flags, then 64 lanes broadcast 64
// line-padded done slots; waiter bid polls slot bid>>3 (8 pollers/line).
// Timeouts degrade a residency failure to wrong results, not a hang.
__device__ __forceinline__ void gbar(int* flags, int* done, int idx) {
    asm volatile("s_waitcnt vmcnt(0) lgkmcnt(0)" ::: "memory");
    __syncthreads();
    const int bid = blockIdx.x, tid = threadIdx.x;
    if (bid == 0) {
        if (tid == 0)
            __hip_atomic_store(&flags[idx * NBLK], 1,
                               __ATOMIC_RELAXED, __HIP_MEMORY_SCOPE_AGENT);
        int* base = flags + idx * NBLK;
        int spins = 0;
        for (;;) {
            int v0 = __hip_atomic_load(&base[tid], __ATOMIC_RELAXED,
                                       __HIP_MEMORY_SCOPE_AGENT);
            int v1 = __hip_atomic_load(&base[256 + tid], __ATOMIC_RELAXED,
                                       __HIP_MEMORY_SCOPE_AGENT);
            if (__syncthreads_and(v0 & v1)) break;
            if (++spins > (1 << 20)) break;
            __builtin_amdgcn_s_sleep(1);
        }
        if (tid < 64)
            __hip_atomic_store(&done[(idx * 64 + tid) * 16], 1,
                               __ATOMIC_RELAXED, __HIP_MEMORY_SCOPE_AGENT);
        __syncthreads();
    } else {
        if (tid == 0) {
            __hip_atomic_store(&flags[idx * NBLK + bid], 1,
                               __ATOMIC_RELAXED, __HIP_MEMORY_SCOPE_AGENT);
            const int g = bid >> 3;
            int spins = 0;
            while (__hip_atomic_load(&done[(idx * 64 + g) * 16], __ATOMIC_RELAXED,
                                     __HIP_MEMORY_SCOPE_AGENT) == 0
                   && spins < (1 << 22)) {
                __builtin_amdgcn_s_sleep(16);
                ++spins;
            }
        }
        __syncthreads();
    }
}

__global__ void __launch_bounds__(256, 2) k_all(
    const float* __restrict__ nf, const float* __restrict__ adj,
    const float* __restrict__ wvu, const float* __restrict__ Wi,
    const float* __restrict__ bi, const float* __restrict__ Wee,
    const float* __restrict__ Wef, const float* __restrict__ Wm,
    const float* __restrict__ Wu, float* __restrict__ out,
    float* __restrict__ x0buf, float* __restrict__ x1buf,
    float* __restrict__ normf, int* __restrict__ flags, int* __restrict__ done)
{
    __shared__ SMem sm;
    __shared__ float wq[512][4];     // persistent: this block's 4 Wfull rows (wT layout)
    __shared__ float snorm[4];
    __shared__ float swmax[4];
    const int bid = blockIdx.x, tid = threadIdx.x;
    const int g0 = bid * 4;
    const int b = g0 >> 10, i0 = g0 & 1023;
    const bool top = (i0 < 512);
    const int lane = tid & 63, wave = tid >> 6;

    // ---------- Phase A: norm colsum partials (atomicAdd, exact) + x0 -------
    {
        int cb = bid >> 8, cc = (bid >> 6) & 3, rc = bid & 63;
        int col = cc * 256 + tid;
        const float* p = adj + (size_t)cb * NTOT * NTOT + (size_t)rc * 16 * NTOT + col;
        float s = 0.f;
#pragma unroll
        for (int r = 0; r < 16; ++r) s += 1.0f - p[(size_t)r * NTOT];
        atomicAdd(&normf[cb * NTOT + col], s);
    }
    float xreg;   // own x[g0+q][f] kept in register across layers
    {
        int e = bid * 256 + tid;        // == (g0+q)*64 + f
        int f0 = e & 63, bn = e >> 6;
        xreg = fmaxf(fmaf(nf[bn], Wi[f0], bi[f0]), 0.f);
        st_coh(&x0buf[e], xreg);
    }
    // ---------- own w rows straight from wvu (no transpose kernel) ----------
    if (top) {
        // wq[j][r] = wvu[b][j][i0+r]  (gather 4-wide column slab, 512 float4s)
        const float4* base = (const float4*)(wvu + (size_t)b * 262144 + i0);
        float4 v0 = base[(size_t)(2 * tid) * 128];
        float4 v1 = base[(size_t)(2 * tid + 1) * 128];
        *(float4*)&wq[2 * tid][0] = v0;
        *(float4*)&wq[2 * tid + 1][0] = v1;
    } else {
        // wq[j][r] = wvu[b][i0-512+r][j]  (4 contiguous rows)
        const float* wsrc = wvu + (size_t)b * 262144 + (size_t)(i0 - 512) * 512;
        for (int t = tid; t < 2048; t += 256) {
            int r = t >> 9, j = t & 511;
            wq[j][r] = wsrc[r * 512 + j];
        }
    }
    // ---------- stage EdgeS parts with no cross-block deps (hide under bar0)
    {
        const float4* src = (const float4*)(adj + (size_t)b * 1048576 + (size_t)i0 * 1024);
        float4* dst = (float4*)sm.e.adjr;
        for (int t = tid; t < 1024; t += 256) dst[t] = src[t];
        const float4* nsrc = (const float4*)(nf + b * 1024);
        ((float4*)sm.e.nfv)[tid] = nsrc[tid];
        const float4* wefs = (const float4*)Wef;
        float4* wefd = (float4*)sm.e.wef;
        for (int t = tid; t < 1024; t += 256) wefd[t] = wefs[t];
    }
    gbar(flags, done, 0);

    // ---------- post-bar0: w edge-layout copy, own norms, global max --------
    for (int t = tid; t < 2048; t += 256) {
        int r = t >> 9, j = t & 511;
        sm.e.w[r][j] = wq[j][r];
    }
    if (tid < 4) snorm[tid] = fmaxf(ld_coh(&normf[b * NTOT + i0 + tid]), 1.0f);
    {
        float m = 1.0f;
#pragma unroll
        for (int u = 0; u < 8; ++u)
            m = fmaxf(m, ld_coh(&normf[tid * 8 + u]));
#pragma unroll
        for (int o = 32; o > 0; o >>= 1) m = fmaxf(m, __shfl_xor(m, o, 64));
        if (lane == 0) swmax[wave] = m;
    }
    __syncthreads();

    // ---------- Phase C: edge embedding (result kept in registers) ----------
    float eval;
    {
        int row = wave;
        int sameoff = top ? 0 : 512;
        int crossoff = top ? 512 : 0;
        float sp = 0.f, smv = 0.f;
#pragma unroll
        for (int it = 0; it < 8; ++it) {
            int j = sameoff + it * 64 + lane;
            float m = 1.0f - sm.e.adjr[row][j];
            float x = sm.e.nfv[j];
            sp = fmaf(m, fmaxf(x, 0.f), sp);
            smv = fmaf(m, fmaxf(-x, 0.f), smv);
        }
#pragma unroll
        for (int o = 32; o > 0; o >>= 1) {
            sp += __shfl_xor(sp, o, 64);
            smv += __shfl_xor(smv, o, 64);
        }
        float W0 = 0.f, W1 = 0.f;
        if (lane < 63) { W0 = Wee[lane]; W1 = Wee[63 + lane]; }
        float acc = fabsf(W1) * (W1 > 0.f ? sp : smv);
        const float* arow = &sm.e.adjr[row][crossoff];
        const float* nrow = &sm.e.nfv[crossoff];
        const float* wrow = &sm.e.w[row][0];
#pragma unroll 4
        for (int qq = 0; qq < 128; ++qq) {
            float4 a4 = *(const float4*)(arow + qq * 4);
            float4 w4 = *(const float4*)(wrow + qq * 4);
            float4 n4 = *(const float4*)(nrow + qq * 4);
            float c;
            c = fmaxf(fmaf(w4.x, W0, n4.x * W1), 0.f); acc = fmaf(1.0f - a4.x, c, acc);
            c = fmaxf(fmaf(w4.y, W0, n4.y * W1), 0.f); acc = fmaf(1.0f - a4.y, c, acc);
            c = fmaxf(fmaf(w4.z, W0, n4.z * W1), 0.f); acc = fmaf(1.0f - a4.z, c, acc);
            c = fmaxf(fmaf(w4.w, W0, n4.w * W1), 0.f); acc = fmaf(1.0f - a4.w, c, acc);
        }
        float nv = snorm[row];
        float nmaxv = fmaxf(fmaxf(swmax[0], swmax[1]), fmaxf(swmax[2], swmax[3]));
        float ein = (lane < 63) ? (acc * (1.0f / nv)) : (nv / nmaxv);
        sm.e.ein[row][lane] = ein;
        __syncthreads();
        float acc2 = 0.f;
#pragma unroll
        for (int c = 0; c < 64; ++c)
            acc2 = fmaf(sm.e.ein[row][c], sm.e.wef[c][lane], acc2);
        eval = fmaxf(acc2, 0.f);
    }
    __syncthreads();   // EdgeS reads done; union switches to LayerS

    // ---------- Layers: e + own-x in regs, w from persistent wq -------------
    const int f = lane, q = wave;
    sm.l.e[q][f] = eval;
    const float rnorm = 1.0f / snorm[q];

    for (int l = 0; l < 4; ++l) {
        const float* xin = (l & 1) ? x1buf : x0buf;
        float* xout = (l == 3) ? out : ((l & 1) ? x0buf : x1buf);
        const float* WmL = Wm + l * 8192;
        const float* WuL = Wu + l * 8192;

        sm.l.x[q][f] = xreg;            // own row from register, no reload
        __syncthreads();

        const float* xb = xin + ((size_t)b * 1024 + (top ? 512 : 0)) * 64 + f;
        float a0 = 0, a1 = 0, a2 = 0, a3 = 0;
#pragma unroll
        for (int jo = 0; jo < 128; jo += 32) {
            float xv[32];
#pragma unroll
            for (int u = 0; u < 32; ++u)
                xv[u] = ld_coh(xb + (size_t)(q * 128 + jo + u) * 64);
#pragma unroll
            for (int u = 0; u < 32; ++u) {
                int j = q * 128 + jo + u;
                float4 w4 = *(const float4*)&wq[j][0];
                a0 = fmaf(w4.x, xv[u], a0);
                a1 = fmaf(w4.y, xv[u], a1);
                a2 = fmaf(w4.z, xv[u], a2);
                a3 = fmaf(w4.w, xv[u], a3);
            }
        }
        sm.l.part[q][0][f] = a0; sm.l.part[q][1][f] = a1;
        sm.l.part[q][2][f] = a2; sm.l.part[q][3][f] = a3;
        __syncthreads();
        float aggv = (sm.l.part[0][q][f] + sm.l.part[1][q][f] +
                      sm.l.part[2][q][f] + sm.l.part[3][q][f]) * rnorm;
        sm.l.agg[q][f] = aggv;
        __syncthreads();
        float mv = 0.f;
#pragma unroll 4
        for (int c = 0; c < 64; ++c) mv = fmaf(sm.l.agg[q][c], WmL[c * 64 + f], mv);
#pragma unroll 4
        for (int c = 0; c < 64; ++c) mv = fmaf(sm.l.e[q][c], WmL[(64 + c) * 64 + f], mv);
        mv = fmaxf(mv, 0.f);
        sm.l.msg[q][f] = mv;
        __syncthreads();
        float h = 0.f;
#pragma unroll 4
        for (int c = 0; c < 64; ++c) h = fmaf(sm.l.x[q][c], WuL[c * 64 + f], h);
#pragma unroll 4
        for (int c = 0; c < 64; ++c) h = fmaf(sm.l.msg[q][c], WuL[(64 + c) * 64 + f], h);
        if (l != 3) {
            h = fmaxf(h, 0.f);
            st_coh(&xout[(size_t)(g0 + q) * 64 + f], h);
            xreg = h;
            gbar(flags, done, 1 + l);
        } else {
            xout[(size_t)(g0 + q) * 64 + f] = h;   // final: normal store
        }
    }
}

extern "C" void kernel_launch(void* const* d_in, const int* in_sizes, int n_in,
                              void* d_out, int out_size, void* d_ws, size_t ws_size,
                              hipStream_t stream) {
    const float* nf  = (const float*)d_in[0];
    const float* adj = (const float*)d_in[1];
    const float* wvu = (const float*)d_in[2];
    const float* Wi  = (const float*)d_in[3];
    const float* bi  = (const float*)d_in[4];
    const float* Wee = (const float*)d_in[5];
    const float* Wef = (const float*)d_in[6];
    const float* Wm  = (const float*)d_in[7];
    const float* Wu  = (const float*)d_in[8];
    float* out = (float*)d_out;
    float* ws = (float*)d_ws;

    float* x0buf = ws;               // 131072 floats
    float* x1buf = ws + 131072;      // 131072
    float* ctrl  = ws + 262144;      // normf[2048] + flags[4*512] + done[4*64*16]
    float* normf = ctrl;
    int*   flags = (int*)(ctrl + 2048);
    int*   done  = (int*)(ctrl + 2048 + 4 * NBLK);

    hipMemsetAsync(ctrl, 0, (2048 + 4 * NBLK + 4 * 64 * 16) * sizeof(float), stream);

    k_all<<<NBLK, 256, 0, stream>>>(nf, adj, wvu, Wi, bi, Wee, Wef, Wm, Wu,
                                    out, x0buf, x1buf, normf, flags, done);
}

// Round 11
// 139.690 us; speedup vs baseline: 4.2809x; 1.3450x over previous
//
#include <hip/hip_runtime.h>

// Problem constants: B=2, N=1024, U=V=512, F_IN=1, F=64, L=4
#define NTOT 1024
#define HALF 512
#define NBLK 256
#define NTHR 512

struct EdgeS  { float adjr[8][1024]; float nfv[1024]; float ein[8][64]; };
struct LayerS { float part[8][8][64]; float e[8][64]; float x[8][64];
                float agg[8][64]; float msg[8][64]; };
union SMem { EdgeS e; LayerS l; };

static __device__ __forceinline__ void st_coh(float* p, float v) {
    __hip_atomic_store(p, v, __ATOMIC_RELAXED, __HIP_MEMORY_SCOPE_AGENT);
}
static __device__ __forceinline__ float ld_coh(const float* p) {
    return __hip_atomic_load((float*)p, __ATOMIC_RELAXED, __HIP_MEMORY_SCOPE_AGENT);
}

// Split barrier. Arrive: drain own coherent stores (per-wave vmcnt), block
// barrier, one padded flag store. Wait: every block polls all 256 flags
// itself (no two-hop broadcast). Timeout degrades to wrong results, no hang.
static __device__ __forceinline__ void gbar_arrive(int* flags, int idx) {
    asm volatile("s_waitcnt vmcnt(0) lgkmcnt(0)" ::: "memory");
    __syncthreads();
    if (threadIdx.x == 0)
        __hip_atomic_store(&flags[idx * NBLK * 16 + blockIdx.x * 16], 1,
                           __ATOMIC_RELAXED, __HIP_MEMORY_SCOPE_AGENT);
}
static __device__ __forceinline__ void gbar_wait(int* flags, int idx) {
    const int tid = threadIdx.x;
    int spins = 0;
    for (;;) {
        int v = 1;
        if (tid < NBLK)
            v = __hip_atomic_load(&flags[idx * NBLK * 16 + tid * 16],
                                  __ATOMIC_RELAXED, __HIP_MEMORY_SCOPE_AGENT);
        if (__syncthreads_and(v != 0)) break;
        if (++spins > (1 << 17)) break;
        if (spins > 2) __builtin_amdgcn_s_sleep(4);
    }
}

__global__ void __launch_bounds__(NTHR, 2) k_all(
    const float* __restrict__ nf, const float* __restrict__ adj,
    const float* __restrict__ wvu, const float* __restrict__ Wi,
    const float* __restrict__ bi, const float* __restrict__ Wee,
    const float* __restrict__ Wef, const float* __restrict__ Wm,
    const float* __restrict__ Wu, float* __restrict__ out,
    float* __restrict__ x0buf, float* __restrict__ x1buf,
    float* __restrict__ normf, int* __restrict__ flags)
{
    __shared__ SMem sm;
    __shared__ float wqv[512][8];   // persistent: W for this block's 8 rows
    __shared__ float snorm[8];
    __shared__ float swred[8];
    const int bid = blockIdx.x, tid = threadIdx.x;
    const int g0 = bid * 8;
    const int b = g0 >> 10, i0 = g0 & 1023;
    const bool top = (i0 < 512);
    const int lane = tid & 63, wave = tid >> 6;   // wave = row q / j-chunk

    // ---------- Phase A: norm colsum partials (exact atomicAdd) + x0 --------
    {
        int cb = bid >> 7, sub = bid & 127;
        int cc = sub & 1, rc = sub >> 1;
        int col = cc * 512 + tid;
        const float* p = adj + (size_t)cb * NTOT * NTOT + (size_t)rc * 16 * NTOT + col;
        float s = 0.f;
#pragma unroll
        for (int r = 0; r < 16; ++r) s += 1.0f - p[(size_t)r * NTOT];
        atomicAdd(&normf[cb * NTOT + col], s);
    }
    float xreg;   // own x[g0+q][f], lives in a register across layers
    {
        int e = bid * NTHR + tid;       // == (g0+q)*64 + f
        int f0 = e & 63, bn = e >> 6;
        xreg = fmaxf(fmaf(nf[bn], Wi[f0], bi[f0]), 0.f);
        st_coh(&x0buf[e], xreg);
    }
    gbar_arrive(flags, 0);   // normf partials + x^0 published

    // ---------- stage wqv + adjr + nfv (overlaps bar0 skew) -----------------
    if (top) {
        // wqv[j][r] = wvu[b][j][i0+r]
        const float* src = wvu + (size_t)b * 262144 + (size_t)tid * 512 + i0;
        float4 v0 = *(const float4*)(src);
        float4 v1 = *(const float4*)(src + 4);
        *(float4*)&wqv[tid][0] = v0;
        *(float4*)&wqv[tid][4] = v1;
    } else {
        // wqv[j][r] = wvu[b][i0-512+r][j]
        const float* wsrc = wvu + (size_t)b * 262144 + (size_t)(i0 - 512) * 512;
        for (int t = tid; t < 4096; t += NTHR) {
            int r = t >> 9, j = t & 511;
            wqv[j][r] = wsrc[r * 512 + j];
        }
    }
    {
        const float4* asrc = (const float4*)(adj + (size_t)b * 1048576 + (size_t)i0 * 1024);
        float4* adst = (float4*)sm.e.adjr;
        for (int t = tid; t < 2048; t += NTHR) adst[t] = asrc[t];
        if (tid < 256) ((float4*)sm.e.nfv)[tid] = ((const float4*)(nf + b * 1024))[tid];
    }
    __syncthreads();

    // ---------- edge compute that needs no cross-block data -----------------
    const int row = wave;
    float acc;
    {
        int sameoff = top ? 0 : 512;
        int crossoff = top ? 512 : 0;
        float sp = 0.f, smv = 0.f;
#pragma unroll
        for (int it = 0; it < 8; ++it) {
            int j = sameoff + it * 64 + lane;
            float m = 1.0f - sm.e.adjr[row][j];
            float x = sm.e.nfv[j];
            sp = fmaf(m, fmaxf(x, 0.f), sp);
            smv = fmaf(m, fmaxf(-x, 0.f), smv);
        }
#pragma unroll
        for (int o = 32; o > 0; o >>= 1) {
            sp += __shfl_xor(sp, o, 64);
            smv += __shfl_xor(smv, o, 64);
        }
        float W0 = 0.f, W1 = 0.f;
        if (lane < 63) { W0 = Wee[lane]; W1 = Wee[63 + lane]; }
        acc = fabsf(W1) * (W1 > 0.f ? sp : smv);
        const float* arow = &sm.e.adjr[row][crossoff];
        const float* nrow = &sm.e.nfv[crossoff];
#pragma unroll 4
        for (int qq = 0; qq < 128; ++qq) {
            float4 a4 = *(const float4*)(arow + qq * 4);
            float4 n4 = *(const float4*)(nrow + qq * 4);
            float w0 = wqv[qq * 4 + 0][row];
            float w1 = wqv[qq * 4 + 1][row];
            float w2 = wqv[qq * 4 + 2][row];
            float w3 = wqv[qq * 4 + 3][row];
            float c;
            c = fmaxf(fmaf(w0, W0, n4.x * W1), 0.f); acc = fmaf(1.0f - a4.x, c, acc);
            c = fmaxf(fmaf(w1, W0, n4.y * W1), 0.f); acc = fmaf(1.0f - a4.y, c, acc);
            c = fmaxf(fmaf(w2, W0, n4.z * W1), 0.f); acc = fmaf(1.0f - a4.z, c, acc);
            c = fmaxf(fmaf(w3, W0, n4.w * W1), 0.f); acc = fmaf(1.0f - a4.w, c, acc);
        }
    }
    gbar_wait(flags, 0);   // normf + x^0 now globally visible

    // ---------- norms (own 8 + global max) ----------------------------------
    if (tid < 8) snorm[tid] = fmaxf(ld_coh(&normf[b * NTOT + i0 + tid]), 1.0f);
    {
        float m = 1.0f;
#pragma unroll
        for (int u = 0; u < 4; ++u)
            m = fmaxf(m, ld_coh(&normf[tid * 4 + u]));
#pragma unroll
        for (int o = 32; o > 0; o >>= 1) m = fmaxf(m, __shfl_xor(m, o, 64));
        if (lane == 0) swred[wave] = m;
    }
    __syncthreads();

    // ---------- finish edge: divide, 64x64 matmul (Wef from global/L1) ------
    float eval;
    {
        float nv = snorm[row];
        float nmaxv = fmaxf(fmaxf(fmaxf(swred[0], swred[1]), fmaxf(swred[2], swred[3])),
                            fmaxf(fmaxf(swred[4], swred[5]), fmaxf(swred[6], swred[7])));
        float ein = (lane < 63) ? (acc * (1.0f / nv)) : (nv / nmaxv);
        sm.e.ein[row][lane] = ein;
        __syncthreads();
        float acc2 = 0.f;
#pragma unroll 8
        for (int c = 0; c < 64; ++c)
            acc2 = fmaf(sm.e.ein[row][c], Wef[c * 64 + lane], acc2);
        eval = fmaxf(acc2, 0.f);
    }
    __syncthreads();   // EdgeS dead; union switches to LayerS

    // ---------- layers ------------------------------------------------------
    const int f = lane, q = wave;
    sm.l.e[q][f] = eval;
    sm.l.x[q][f] = xreg;
    __syncthreads();
    const float rnorm = 1.0f / snorm[q];

    for (int l = 0; l < 4; ++l) {
        const float* WmL = Wm + l * 8192;
        const float* WuL = Wu + l * 8192;
        // pre-barrier work: e@Wm2 and own-x@Wu1 (no cross-block deps)
        float emsg = 0.f, hx = 0.f;
#pragma unroll 8
        for (int c = 0; c < 64; ++c) {
            emsg = fmaf(sm.l.e[q][c], WmL[(64 + c) * 64 + f], emsg);
            hx   = fmaf(sm.l.x[q][c], WuL[c * 64 + f], hx);
        }
        if (l > 0) gbar_wait(flags, l);   // x^l cross-half visible

        const float* xin = (l & 1) ? x1buf : x0buf;
        const float* xb = xin + ((size_t)b * 1024 + (top ? 512 : 0)) * 64 + f;
        float a0 = 0, a1 = 0, a2 = 0, a3 = 0, a4 = 0, a5 = 0, a6 = 0, a7 = 0;
        const int jbase = q * 64;
#pragma unroll
        for (int hh = 0; hh < 2; ++hh) {
            float xv[32];
#pragma unroll
            for (int u = 0; u < 32; ++u)
                xv[u] = ld_coh(xb + (size_t)(jbase + hh * 32 + u) * 64);
#pragma unroll
            for (int u = 0; u < 32; ++u) {
                int j = jbase + hh * 32 + u;
                float4 w0 = *(const float4*)&wqv[j][0];
                float4 w1 = *(const float4*)&wqv[j][4];
                a0 = fmaf(w0.x, xv[u], a0); a1 = fmaf(w0.y, xv[u], a1);
                a2 = fmaf(w0.z, xv[u], a2); a3 = fmaf(w0.w, xv[u], a3);
                a4 = fmaf(w1.x, xv[u], a4); a5 = fmaf(w1.y, xv[u], a5);
                a6 = fmaf(w1.z, xv[u], a6); a7 = fmaf(w1.w, xv[u], a7);
            }
        }
        sm.l.part[q][0][f] = a0; sm.l.part[q][1][f] = a1;
        sm.l.part[q][2][f] = a2; sm.l.part[q][3][f] = a3;
        sm.l.part[q][4][f] = a4; sm.l.part[q][5][f] = a5;
        sm.l.part[q][6][f] = a6; sm.l.part[q][7][f] = a7;
        __syncthreads();
        float aggv = 0.f;
#pragma unroll
        for (int w = 0; w < 8; ++w) aggv += sm.l.part[w][q][f];
        aggv *= rnorm;
        sm.l.agg[q][f] = aggv;
        __syncthreads();
        float mv = emsg;
#pragma unroll 8
        for (int c = 0; c < 64; ++c) mv = fmaf(sm.l.agg[q][c], WmL[c * 64 + f], mv);
        mv = fmaxf(mv, 0.f);
        sm.l.msg[q][f] = mv;
        __syncthreads();
        float h = hx;
#pragma unroll 8
        for (int c = 0; c < 64; ++c) h = fmaf(sm.l.msg[q][c], WuL[(64 + c) * 64 + f], h);
        if (l != 3) {
            h = fmaxf(h, 0.f);
            float* xout = (l & 1) ? x0buf : x1buf;
            st_coh(&xout[(size_t)(g0 + q) * 64 + f], h);
            xreg = h;
            sm.l.x[q][f] = h;               // published by arrive's syncthreads
            gbar_arrive(flags, l + 1);
        } else {
            out[(size_t)(g0 + q) * 64 + f] = h;
        }
    }
}

extern "C" void kernel_launch(void* const* d_in, const int* in_sizes, int n_in,
                              void* d_out, int out_size, void* d_ws, size_t ws_size,
                              hipStream_t stream) {
    const float* nf  = (const float*)d_in[0];
    const float* adj = (const float*)d_in[1];
    const float* wvu = (const float*)d_in[2];
    const float* Wi  = (const float*)d_in[3];
    const float* bi  = (const float*)d_in[4];
    const float* Wee = (const float*)d_in[5];
    const float* Wef = (const float*)d_in[6];
    const float* Wm  = (const float*)d_in[7];
    const float* Wu  = (const float*)d_in[8];
    float* out = (float*)d_out;
    float* ws = (float*)d_ws;

    float* x0buf = ws;               // 131072 floats
    float* x1buf = ws + 131072;      // 131072
    float* ctrl  = ws + 262144;      // normf[2048] + flags[4*256*16]
    float* normf = ctrl;
    int*   flags = (int*)(ctrl + 2048);

    hipMemsetAsync(ctrl, 0, (2048 + 4 * NBLK * 16) * sizeof(float), stream);

    k_all<<<NBLK, NTHR, 0, stream>>>(nf, adj, wvu, Wi, bi, Wee, Wef, Wm, Wu,
                                     out, x0buf, x1buf, normf, flags);
}

// Round 12
// 139.580 us; speedup vs baseline: 4.2842x; 1.0008x over previous
//
#include <hip/hip_runtime.h>

// Problem constants: B=2, N=1024, U=V=512, F_IN=1, F=64, L=4
#define NTOT 1024
#define HALF 512
#define NBLK 256
#define NTHR 512

struct EdgeS  { float adjr[8][1024]; float nfv[1024]; float ein[8][64]; };
struct LayerS { float part[8][8][64]; float e[8][64]; float x[8][64];
                float agg[8][64]; float msg[8][64]; };
union SMem { EdgeS e; LayerS l; };

static __device__ __forceinline__ void st_coh(float* p, float v) {
    __hip_atomic_store(p, v, __ATOMIC_RELAXED, __HIP_MEMORY_SCOPE_AGENT);
}
static __device__ __forceinline__ float ld_coh(const float* p) {
    return __hip_atomic_load((float*)p, __ATOMIC_RELAXED, __HIP_MEMORY_SCOPE_AGENT);
}

// Split barrier. Arrive: drain own coherent stores (per-wave vmcnt), block
// barrier, one padded flag store. Waits poll only the flags they depend on.
// Timeouts degrade a residency failure to wrong results, not a hang.
static __device__ __forceinline__ void gbar_arrive(int* flags, int idx) {
    asm volatile("s_waitcnt vmcnt(0) lgkmcnt(0)" ::: "memory");
    __syncthreads();
    if (threadIdx.x == 0)
        __hip_atomic_store(&flags[idx * NBLK * 16 + blockIdx.x * 16], 1,
                           __ATOMIC_RELAXED, __HIP_MEMORY_SCOPE_AGENT);
}
// global wait: all 256 flags (used only for bar0, hidden under edge compute)
static __device__ __forceinline__ void gbar_wait_all(int* flags, int idx) {
    const int tid = threadIdx.x;
    int spins = 0;
    for (;;) {
        int v = 1;
        if (tid < NBLK)
            v = __hip_atomic_load(&flags[idx * NBLK * 16 + tid * 16],
                                  __ATOMIC_RELAXED, __HIP_MEMORY_SCOPE_AGENT);
        if (__syncthreads_and(v != 0)) break;
        if (++spins > (1 << 17)) break;
        if (spins > 2) __builtin_amdgcn_s_sleep(4);
    }
}
// partial wait: only the 64 producer blocks we actually read from
static __device__ __forceinline__ void gbar_wait64(int* flags, int idx, int pbase) {
    const int tid = threadIdx.x;
    int spins = 0;
    for (;;) {
        int v = 1;
        if (tid < 64)
            v = __hip_atomic_load(&flags[idx * NBLK * 16 + (pbase + tid) * 16],
                                  __ATOMIC_RELAXED, __HIP_MEMORY_SCOPE_AGENT);
        if (__syncthreads_and(v != 0)) break;
        if (++spins > (1 << 17)) break;
        if (spins > 1) __builtin_amdgcn_s_sleep(1);
    }
}

__global__ void __launch_bounds__(NTHR, 2) k_all(
    const float* __restrict__ nf, const float* __restrict__ adj,
    const float* __restrict__ wvu, const float* __restrict__ Wi,
    const float* __restrict__ bi, const float* __restrict__ Wee,
    const float* __restrict__ Wef, const float* __restrict__ Wm,
    const float* __restrict__ Wu, float* __restrict__ out,
    float* __restrict__ x0buf, float* __restrict__ x1buf,
    float* __restrict__ normf, int* __restrict__ flags)
{
    __shared__ SMem sm;
    __shared__ float wqv[512][8];   // persistent: W for this block's 8 rows
    __shared__ float snorm[8];
    __shared__ float swred[8];
    const int bid = blockIdx.x, tid = threadIdx.x;
    const int g0 = bid * 8;
    const int b = g0 >> 10, i0 = g0 & 1023;
    const bool top = (i0 < 512);
    const int lane = tid & 63, wave = tid >> 6;   // wave = row q / j-chunk
    // producers of the cross-half x this block reads each layer:
    const int pbase = b * 128 + (top ? 64 : 0);

    // ---------- Phase A: norm colsum partials (exact atomicAdd) + x0 --------
    {
        int cb = bid >> 7, sub = bid & 127;
        int cc = sub & 1, rc = sub >> 1;
        int col = cc * 512 + tid;
        const float* p = adj + (size_t)cb * NTOT * NTOT + (size_t)rc * 16 * NTOT + col;
        float s = 0.f;
#pragma unroll
        for (int r = 0; r < 16; ++r) s += 1.0f - p[(size_t)r * NTOT];
        atomicAdd(&normf[cb * NTOT + col], s);
    }
    float xreg;   // own x[g0+q][f], lives in a register across layers
    {
        int e = bid * NTHR + tid;       // == (g0+q)*64 + f
        int f0 = e & 63, bn = e >> 6;
        xreg = fmaxf(fmaf(nf[bn], Wi[f0], bi[f0]), 0.f);
        st_coh(&x0buf[e], xreg);
    }
    gbar_arrive(flags, 0);   // normf partials + x^0 published

    // ---------- stage wqv + adjr + nfv (overlaps bar0 skew) -----------------
    if (top) {
        // wqv[j][r] = wvu[b][j][i0+r]
        const float* src = wvu + (size_t)b * 262144 + (size_t)tid * 512 + i0;
        float4 v0 = *(const float4*)(src);
        float4 v1 = *(const float4*)(src + 4);
        *(float4*)&wqv[tid][0] = v0;
        *(float4*)&wqv[tid][4] = v1;
    } else {
        // wqv[j][r] = wvu[b][i0-512+r][j]
        const float* wsrc = wvu + (size_t)b * 262144 + (size_t)(i0 - 512) * 512;
        for (int t = tid; t < 4096; t += NTHR) {
            int r = t >> 9, j = t & 511;
            wqv[j][r] = wsrc[r * 512 + j];
        }
    }
    {
        const float4* asrc = (const float4*)(adj + (size_t)b * 1048576 + (size_t)i0 * 1024);
        float4* adst = (float4*)sm.e.adjr;
        for (int t = tid; t < 2048; t += NTHR) adst[t] = asrc[t];
        if (tid < 256) ((float4*)sm.e.nfv)[tid] = ((const float4*)(nf + b * 1024))[tid];
    }
    __syncthreads();

    // ---------- edge compute that needs no cross-block data -----------------
    const int row = wave;
    float acc;
    {
        int sameoff = top ? 0 : 512;
        int crossoff = top ? 512 : 0;
        float sp = 0.f, smv = 0.f;
#pragma unroll
        for (int it = 0; it < 8; ++it) {
            int j = sameoff + it * 64 + lane;
            float m = 1.0f - sm.e.adjr[row][j];
            float x = sm.e.nfv[j];
            sp = fmaf(m, fmaxf(x, 0.f), sp);
            smv = fmaf(m, fmaxf(-x, 0.f), smv);
        }
#pragma unroll
        for (int o = 32; o > 0; o >>= 1) {
            sp += __shfl_xor(sp, o, 64);
            smv += __shfl_xor(smv, o, 64);
        }
        float W0 = 0.f, W1 = 0.f;
        if (lane < 63) { W0 = Wee[lane]; W1 = Wee[63 + lane]; }
        acc = fabsf(W1) * (W1 > 0.f ? sp : smv);
        const float* arow = &sm.e.adjr[row][crossoff];
        const float* nrow = &sm.e.nfv[crossoff];
#pragma unroll 4
        for (int qq = 0; qq < 128; ++qq) {
            float4 a4 = *(const float4*)(arow + qq * 4);
            float4 n4 = *(const float4*)(nrow + qq * 4);
            float w0 = wqv[qq * 4 + 0][row];
            float w1 = wqv[qq * 4 + 1][row];
            float w2 = wqv[qq * 4 + 2][row];
            float w3 = wqv[qq * 4 + 3][row];
            float c;
            c = fmaxf(fmaf(w0, W0, n4.x * W1), 0.f); acc = fmaf(1.0f - a4.x, c, acc);
            c = fmaxf(fmaf(w1, W0, n4.y * W1), 0.f); acc = fmaf(1.0f - a4.y, c, acc);
            c = fmaxf(fmaf(w2, W0, n4.z * W1), 0.f); acc = fmaf(1.0f - a4.z, c, acc);
            c = fmaxf(fmaf(w3, W0, n4.w * W1), 0.f); acc = fmaf(1.0f - a4.w, c, acc);
        }
    }
    gbar_wait_all(flags, 0);   // normf + x^0 now globally visible

    // ---------- norms (own 8 + global max) ----------------------------------
    if (tid < 8) snorm[tid] = fmaxf(ld_coh(&normf[b * NTOT + i0 + tid]), 1.0f);
    {
        float m = 1.0f;
#pragma unroll
        for (int u = 0; u < 4; ++u)
            m = fmaxf(m, ld_coh(&normf[tid * 4 + u]));
#pragma unroll
        for (int o = 32; o > 0; o >>= 1) m = fmaxf(m, __shfl_xor(m, o, 64));
        if (lane == 0) swred[wave] = m;
    }
    __syncthreads();

    // ---------- finish edge: divide, 64x64 matmul (Wef from global/L1) ------
    float eval;
    {
        float nv = snorm[row];
        float nmaxv = fmaxf(fmaxf(fmaxf(swred[0], swred[1]), fmaxf(swred[2], swred[3])),
                            fmaxf(fmaxf(swred[4], swred[5]), fmaxf(swred[6], swred[7])));
        float ein = (lane < 63) ? (acc * (1.0f / nv)) : (nv / nmaxv);
        sm.e.ein[row][lane] = ein;
        __syncthreads();
        float acc2 = 0.f;
#pragma unroll 8
        for (int c = 0; c < 64; ++c)
            acc2 = fmaf(sm.e.ein[row][c], Wef[c * 64 + lane], acc2);
        eval = fmaxf(acc2, 0.f);
    }
    __syncthreads();   // EdgeS dead; union switches to LayerS

    // ---------- layers ------------------------------------------------------
    const int f = lane, q = wave;
    sm.l.e[q][f] = eval;
    sm.l.x[q][f] = xreg;
    __syncthreads();
    const float rnorm = 1.0f / snorm[q];

    for (int l = 0; l < 4; ++l) {
        const float* WmL = Wm + l * 8192;
        const float* WuL = Wu + l * 8192;
        // pre-barrier work: e@Wm2 and own-x@Wu1 (no cross-block deps)
        float emsg = 0.f, hx = 0.f;
#pragma unroll 8
        for (int c = 0; c < 64; ++c) {
            emsg = fmaf(sm.l.e[q][c], WmL[(64 + c) * 64 + f], emsg);
            hx   = fmaf(sm.l.x[q][c], WuL[c * 64 + f], hx);
        }
        if (l > 0) gbar_wait64(flags, l, pbase);   // cross-half x^l visible

        const float* xin = (l & 1) ? x1buf : x0buf;
        const float* xb = xin + ((size_t)b * 1024 + (top ? 512 : 0)) * 64 + f;
        float a0 = 0, a1 = 0, a2 = 0, a3 = 0, a4 = 0, a5 = 0, a6 = 0, a7 = 0;
        const int jbase = q * 64;
#pragma unroll
        for (int hh = 0; hh < 2; ++hh) {
            float xv[32];
#pragma unroll
            for (int u = 0; u < 32; ++u)
                xv[u] = ld_coh(xb + (size_t)(jbase + hh * 32 + u) * 64);
#pragma unroll
            for (int u = 0; u < 32; ++u) {
                int j = jbase + hh * 32 + u;
                float4 w0 = *(const float4*)&wqv[j][0];
                float4 w1 = *(const float4*)&wqv[j][4];
                a0 = fmaf(w0.x, xv[u], a0); a1 = fmaf(w0.y, xv[u], a1);
                a2 = fmaf(w0.z, xv[u], a2); a3 = fmaf(w0.w, xv[u], a3);
                a4 = fmaf(w1.x, xv[u], a4); a5 = fmaf(w1.y, xv[u], a5);
                a6 = fmaf(w1.z, xv[u], a6); a7 = fmaf(w1.w, xv[u], a7);
            }
        }
        sm.l.part[q][0][f] = a0; sm.l.part[q][1][f] = a1;
        sm.l.part[q][2][f] = a2; sm.l.part[q][3][f] = a3;
        sm.l.part[q][4][f] = a4; sm.l.part[q][5][f] = a5;
        sm.l.part[q][6][f] = a6; sm.l.part[q][7][f] = a7;
        __syncthreads();
        float aggv = 0.f;
#pragma unroll
        for (int w = 0; w < 8; ++w) aggv += sm.l.part[w][q][f];
        aggv *= rnorm;
        sm.l.agg[q][f] = aggv;
        __syncthreads();
        float mv = emsg;
#pragma unroll 8
        for (int c = 0; c < 64; ++c) mv = fmaf(sm.l.agg[q][c], WmL[c * 64 + f], mv);
        mv = fmaxf(mv, 0.f);
        sm.l.msg[q][f] = mv;
        __syncthreads();
        float h = hx;
#pragma unroll 8
        for (int c = 0; c < 64; ++c) h = fmaf(sm.l.msg[q][c], WuL[(64 + c) * 64 + f], h);
        if (l != 3) {
            h = fmaxf(h, 0.f);
            float* xout = (l & 1) ? x0buf : x1buf;
            st_coh(&xout[(size_t)(g0 + q) * 64 + f], h);
            xreg = h;
            sm.l.x[q][f] = h;               // published by arrive's syncthreads
            gbar_arrive(flags, l + 1);
        } else {
            out[(size_t)(g0 + q) * 64 + f] = h;
        }
    }
}

extern "C" void kernel_launch(void* const* d_in, const int* in_sizes, int n_in,
                              void* d_out, int out_size, void* d_ws, size_t ws_size,
                              hipStream_t stream) {
    const float* nf  = (const float*)d_in[0];
    const float* adj = (const float*)d_in[1];
    const float* wvu = (const float*)d_in[2];
    const float* Wi  = (const float*)d_in[3];
    const float* bi  = (const float*)d_in[4];
    const float* Wee = (const float*)d_in[5];
    const float* Wef = (const float*)d_in[6];
    const float* Wm  = (const float*)d_in[7];
    const float* Wu  = (const float*)d_in[8];
    float* out = (float*)d_out;
    float* ws = (float*)d_ws;

    float* x0buf = ws;               // 131072 floats
    float* x1buf = ws + 131072;      // 131072
    float* ctrl  = ws + 262144;      // normf[2048] + flags[4*256*16]
    float* normf = ctrl;
    int*   flags = (int*)(ctrl + 2048);

    hipMemsetAsync(ctrl, 0, (2048 + 4 * NBLK * 16) * sizeof(float), stream);

    k_all<<<NBLK, NTHR, 0, stream>>>(nf, adj, wvu, Wi, bi, Wee, Wef, Wm, Wu,
                                     out, x0buf, x1buf, normf, flags);
}